// Round 1
// baseline (2343.183 us; speedup 1.0000x reference)
//
#include <hip/hip_runtime.h>
#include <hip/hip_bf16.h>
#include <math.h>

#define BB 8
#define KK 19
#define PP 16384
#define CC 256
#define NN (BB*PP)           // 131072
#define KA_C 10.0f
#define IGNORE_L 255
#define CETHR 0.22314355131420976f   // -log(0.8)

// ws offsets (floats)
#define OFF_PROTO   0               // 4864   [c][k]
#define OFF_COUNTS  4864            // 32
#define OFF_SCAL    4896            // 16 : 0 vmf, 1 consist, 2 ce_num, 3 ce_den, 4 contrast
#define OFF_UINIT   4912            // 4864  [c][k]
#define OFF_U       9776            // 4864  [k][c]
#define OFF_A       14640           // KK*PP = 311296  [k][pix]
#define OFF_RNORM   325936          // NN
#define OFF_PBUF    457008          // BB*KK*PP = 2490368  [b][k][pix]
#define OFF_UPART   2947376         // 512*4864

// ---------------- proto segment-sum ----------------
__global__ __launch_bounds__(256) void proto_kernel(const float* __restrict__ feat,
                                                    const int* __restrict__ target,
                                                    float* __restrict__ ws) {
    int blk = blockIdx.x;            // b*CC + c
    int b = blk >> 8;
    int c = blk & 255;
    int tid = threadIdx.x;
    const float* frow = feat + (size_t)(b*CC + c)*PP;
    const int*   trow = target + (size_t)b*PP;
    float acc[KK];
#pragma unroll
    for (int k=0;k<KK;k++) acc[k]=0.f;
    for (int p0 = tid; p0 < PP; p0 += 256) {
        float v = frow[p0];
        int t = trow[p0];
#pragma unroll
        for (int k=0;k<KK;k++) acc[k] += (t==k) ? v : 0.f;
    }
    __shared__ float part[4][KK];
    int lane = tid & 63, w = tid >> 6;
#pragma unroll
    for (int k=0;k<KK;k++) {
        float v = acc[k];
#pragma unroll
        for (int s=32;s>0;s>>=1) v += __shfl_xor(v, s);
        if (lane==0) part[w][k]=v;
    }
    __syncthreads();
    if (tid < KK) {
        float s = part[0][tid]+part[1][tid]+part[2][tid]+part[3][tid];
        atomicAdd(&ws[OFF_PROTO + c*KK + tid], s);
    }
}

// ---------------- counts ----------------
__global__ __launch_bounds__(256) void counts_kernel(const int* __restrict__ target,
                                                     float* __restrict__ ws) {
    __shared__ int cnt[KK];
    if (threadIdx.x < KK) cnt[threadIdx.x]=0;
    __syncthreads();
    for (int i = blockIdx.x*256 + threadIdx.x; i < NN; i += gridDim.x*256) {
        int t = target[i];
        if (t >= 0 && t < KK) atomicAdd(&cnt[t], 1);
    }
    __syncthreads();
    if (threadIdx.x < KK) atomicAdd(&ws[OFF_COUNTS + threadIdx.x], (float)cnt[threadIdx.x]);
}

// ---------------- setup: u_init, u0, contrast ----------------
__global__ __launch_bounds__(256) void setup_kernel(const float* __restrict__ pd,
                                                    float* __restrict__ ws) {
    int c = threadIdx.x;
    __shared__ float red[256];
    __shared__ float nrm[KK];
    __shared__ float lds_ui[256][KK];
    float cnts[KK], vi[KK];
#pragma unroll
    for (int k=0;k<KK;k++) cnts[k] = ws[OFF_COUNTS+k];
#pragma unroll
    for (int k=0;k<KK;k++) vi[k] = ws[OFF_PROTO + c*KK + k] / (cnts[k] + 1e-6f);
    for (int k=0;k<KK;k++) {
        red[c] = vi[k]*vi[k];
        __syncthreads();
        for (int s=128;s>0;s>>=1){ if (c<s) red[c]+=red[c+s]; __syncthreads(); }
        if (c==0) nrm[k] = fmaxf(sqrtf(red[0]), 1e-12f);
        __syncthreads();
    }
#pragma unroll
    for (int k=0;k<KK;k++) { vi[k] = vi[k]/nrm[k]; lds_ui[c][k] = vi[k]; ws[OFF_UINIT + c*KK + k] = vi[k]; }
    __syncthreads();
    float w0[KK];
#pragma unroll
    for (int k=0;k<KK;k++) w0[k] = (cnts[k]==0.f) ? pd[c*KK+k] : vi[k];
    for (int k=0;k<KK;k++) {
        red[c] = w0[k]*w0[k];
        __syncthreads();
        for (int s=128;s>0;s>>=1){ if (c<s) red[c]+=red[c+s]; __syncthreads(); }
        if (c==0) nrm[k] = fmaxf(sqrtf(red[0]), 1e-12f);
        __syncthreads();
    }
#pragma unroll
    for (int k=0;k<KK;k++) ws[OFF_U + k*CC + c] = w0[k] / nrm[k];
    // contrast loss
    float m[KK]; float Kn=0.f;
#pragma unroll
    for (int k=0;k<KK;k++){ m[k] = (cnts[k]==0.f)?0.f:1.f; Kn += m[k]; }
    float csum = 0.f;
    for (int idx = c; idx < KK*KK; idx += 256) {
        int k1 = idx / KK, k2 = idx % KK;
        if (m[k1]!=0.f && m[k2]!=0.f) {
            float g=0.f;
            for (int cc2=0; cc2<CC; cc2++) g += lds_ui[cc2][k1]*lds_ui[cc2][k2];
            csum += g;
        }
    }
    red[c]=csum; __syncthreads();
    for (int s=128;s>0;s>>=1){ if (c<s) red[c]+=red[c+s]; __syncthreads(); }
    if (c==0) ws[OFF_SCAL+4] = (red[0] - Kn) / (Kn * (Kn - 1.f));
}

// ---------------- P: dis -> p ----------------
__global__ __launch_bounds__(256) void p_kernel(const float* __restrict__ feat,
                                                const float* __restrict__ ws_u,
                                                const float* __restrict__ ws_a,
                                                float* __restrict__ pbuf,
                                                float* __restrict__ rnorm,
                                                int uniform_a) {
    int n = blockIdx.x*256 + threadIdx.x;
    int b = n >> 14;
    int pix = n & (PP-1);
    const float* fcol = feat + (size_t)b*CC*PP + pix;
    float dot[KK];
#pragma unroll
    for (int k=0;k<KK;k++) dot[k]=0.f;
    float ss = 0.f;
    for (int c0=0; c0<CC; c0+=8) {
        float fv[8];
#pragma unroll
        for (int j=0;j<8;j++) fv[j] = fcol[(size_t)(c0+j)*PP];
#pragma unroll
        for (int j=0;j<8;j++) ss = fmaf(fv[j], fv[j], ss);
#pragma unroll
        for (int k=0;k<KK;k++) {
            float d = dot[k];
#pragma unroll
            for (int j=0;j<8;j++) d = fmaf(fv[j], ws_u[k*CC+c0+j], d);
            dot[k]=d;
        }
    }
    float rn = 1.0f / fmaxf(sqrtf(ss), 1e-12f);
    rnorm[n] = rn;
    float e[KK]; float den=0.f;
#pragma unroll
    for (int k=0;k<KK;k++) {
        float av = uniform_a ? (1.0f/(float)KK) : ws_a[k*PP + pix];
        e[k] = av * expf(KA_C * dot[k]*rn);
        den += e[k];
    }
    float inv = 1.0f/den;
#pragma unroll
    for (int k=0;k<KK;k++) pbuf[((size_t)b*KK + k)*PP + pix] = e[k]*inv;
}

// ---------------- A: a = mean_b p ----------------
__global__ __launch_bounds__(256) void a_kernel(const float* __restrict__ pbuf,
                                                float* __restrict__ abuf) {
    int i = blockIdx.x*256 + threadIdx.x;   // KK*PP total
    float s=0.f;
#pragma unroll
    for (int b=0;b<BB;b++) s += pbuf[(size_t)b*KK*PP + i];
    abuf[i] = s * (1.0f/(float)BB);
}

// ---------------- U: Uacc partials ----------------
__global__ __launch_bounds__(256) void u_kernel(const float* __restrict__ feat,
                                                const float* __restrict__ pbuf,
                                                const float* __restrict__ rnorm,
                                                float* __restrict__ upart) {
    int blk = blockIdx.x;           // 512 blocks: b = blk>>6, chunk = blk&63 (256 px each)
    int b = blk >> 6;
    int pix0 = (blk & 63) * 256;
    int tid = threadIdx.x;          // owns c = tid
    __shared__ float lds_f[256][17];
    __shared__ float lds_p[16][20];
    float acc[KK];
#pragma unroll
    for (int k=0;k<KK;k++) acc[k]=0.f;
    const float* fb = feat + (size_t)b*CC*PP;
    for (int st=0; st<16; st++) {
        int ps = pix0 + st*16;
        {
            int pxo = tid & 15;
            int cb  = tid >> 4;
#pragma unroll
            for (int i=0;i<16;i++) {
                int cc = cb*16 + i;
                lds_f[cc][pxo] = fb[(size_t)cc*PP + ps + pxo];
            }
        }
        if (tid < 304) {
            int j = tid / KK, k = tid % KK;
            int px = ps + j;
            lds_p[j][k] = pbuf[((size_t)b*KK + k)*PP + px] * rnorm[(size_t)b*PP + px];
        }
        __syncthreads();
#pragma unroll
        for (int j=0;j<16;j++) {
            float v = lds_f[tid][j];
#pragma unroll
            for (int k=0;k<KK;k++) acc[k] = fmaf(v, lds_p[j][k], acc[k]);
        }
        __syncthreads();
    }
#pragma unroll
    for (int k=0;k<KK;k++) upart[(size_t)blk*4864 + tid*KK + k] = acc[k];
}

// ---------------- R: reduce partials + normalize -> u ----------------
__global__ __launch_bounds__(256) void r_kernel(const float* __restrict__ upart,
                                                float* __restrict__ ws) {
    int k = blockIdx.x;   // 0..18
    int c = threadIdx.x;  // 0..255
    float s = 0.f;
    for (int i=0;i<512;i++) s += upart[(size_t)i*4864 + c*KK + k];
    __shared__ float red[256];
    red[c] = s*s; __syncthreads();
    for (int q=128;q>0;q>>=1){ if (c<q) red[c]+=red[c+q]; __syncthreads(); }
    float nrm = fmaxf(sqrtf(red[0]), 1e-12f);
    ws[OFF_U + k*CC + c] = s / nrm;
}

// ---------------- final losses ----------------
__global__ __launch_bounds__(256) void final_kernel(const float* __restrict__ feat,
                                                    const float* __restrict__ logit,
                                                    const int* __restrict__ target,
                                                    const float* __restrict__ ws_u,
                                                    const float* __restrict__ ws_a,
                                                    float* __restrict__ scal) {
    int n = blockIdx.x*256 + threadIdx.x;
    int b = n >> 14;
    int pix = n & (PP-1);
    const float* fcol = feat + (size_t)b*CC*PP + pix;
    float dot[KK];
#pragma unroll
    for (int k=0;k<KK;k++) dot[k]=0.f;
    float ss = 0.f;
    for (int c0=0; c0<CC; c0+=8) {
        float fv[8];
#pragma unroll
        for (int j=0;j<8;j++) fv[j] = fcol[(size_t)(c0+j)*PP];
#pragma unroll
        for (int j=0;j<8;j++) ss = fmaf(fv[j], fv[j], ss);
#pragma unroll
        for (int k=0;k<KK;k++) {
            float d = dot[k];
#pragma unroll
            for (int j=0;j<8;j++) d = fmaf(fv[j], ws_u[k*CC+c0+j], d);
            dot[k]=d;
        }
    }
    float rn = 1.0f / fmaxf(sqrtf(ss), 1e-12f);
    float e[KK]; float den=0.f; float vmf=0.f;
#pragma unroll
    for (int k=0;k<KK;k++) {
        float av = ws_a[k*PP + pix];
        e[k] = av * expf(KA_C * dot[k]*rn);
        den += e[k];
    }
    float inv = 1.0f/den;
#pragma unroll
    for (int k=0;k<KK;k++) {
        float av = ws_a[k*PP + pix];
        float p = e[k]*inv;
        vmf += -p * (logf(av + 1e-6f) + KA_C * dot[k]*rn);
    }
    // logits
    float lg[KK]; float mx = -3.4e38f;
#pragma unroll
    for (int k=0;k<KK;k++) { lg[k] = logit[((size_t)b*KK + k)*PP + pix]; mx = fmaxf(mx, lg[k]); }
    float sme = 0.f;
#pragma unroll
    for (int k=0;k<KK;k++) sme += expf(lg[k]-mx);
    float lse = mx + logf(sme);
    float cons = 0.f;
#pragma unroll
    for (int k=0;k<KK;k++) cons += -(e[k]*inv) * (lg[k]-lse);
    int t = target[(size_t)b*PP + pix];
    float ce_n = 0.f, ce_d = 0.f;
    if (t != IGNORE_L) {
        float lt = 0.f;
#pragma unroll
        for (int k=0;k<KK;k++) lt = (t==k) ? lg[k] : lt;
        float ce = -(lt - lse);
        ce_n = fmaxf(ce, CETHR);
        ce_d = 1.f;
    }
    // block reduce 4 scalars
    __shared__ float red[4][4];
    int lane = threadIdx.x & 63, w = threadIdx.x >> 6;
    float v0=vmf, v1=cons, v2=ce_n, v3=ce_d;
#pragma unroll
    for (int s=32;s>0;s>>=1) {
        v0 += __shfl_xor(v0, s); v1 += __shfl_xor(v1, s);
        v2 += __shfl_xor(v2, s); v3 += __shfl_xor(v3, s);
    }
    if (lane==0){ red[w][0]=v0; red[w][1]=v1; red[w][2]=v2; red[w][3]=v3; }
    __syncthreads();
    if (threadIdx.x==0) {
        atomicAdd(&scal[0], red[0][0]+red[1][0]+red[2][0]+red[3][0]);
        atomicAdd(&scal[1], red[0][1]+red[1][1]+red[2][1]+red[3][1]);
        atomicAdd(&scal[2], red[0][2]+red[1][2]+red[2][2]+red[3][2]);
        atomicAdd(&scal[3], red[0][3]+red[1][3]+red[2][3]+red[3][3]);
    }
}

// ---------------- finalize ----------------
__global__ __launch_bounds__(256) void finalize_kernel(const float* __restrict__ ws,
                                                       float* __restrict__ out) {
    if (blockIdx.x==0 && threadIdx.x==0) {
        float cnt_all = (float)BB*(float)PP*(float)KK;
        float vmf  = ws[OFF_SCAL+0] / cnt_all / logf((float)KK);
        float cons = ws[OFF_SCAL+1] / cnt_all;
        float ce   = ws[OFF_SCAL+2] / (ws[OFF_SCAL+3] + 1e-6f);
        float contrast = ws[OFF_SCAL+4];
        out[0] = ce + vmf + contrast + cons;
    }
    int i = blockIdx.x*256 + threadIdx.x;
    if (i < 4864) out[1+i] = ws[OFF_PROTO+i];
    if (blockIdx.x==0 && threadIdx.x < KK) out[1+4864+threadIdx.x] = ws[OFF_COUNTS+threadIdx.x];
}

extern "C" void kernel_launch(void* const* d_in, const int* in_sizes, int n_in,
                              void* d_out, int out_size, void* d_ws, size_t ws_size,
                              hipStream_t stream) {
    (void)in_sizes; (void)n_in; (void)out_size; (void)ws_size;
    const float* logit  = (const float*)d_in[0];
    const int*   target = (const int*)d_in[1];
    const float* feat   = (const float*)d_in[2];
    const float* pd     = (const float*)d_in[4];
    float* out = (float*)d_out;
    float* ws  = (float*)d_ws;

    float* ubuf  = ws + OFF_U;
    float* abuf  = ws + OFF_A;
    float* pbuf  = ws + OFF_PBUF;
    float* rnorm = ws + OFF_RNORM;
    float* upart = ws + OFF_UPART;
    float* scal  = ws + OFF_SCAL;

    hipMemsetAsync(ws, 0, OFF_UINIT*sizeof(float), stream);
    proto_kernel<<<BB*CC, 256, 0, stream>>>(feat, target, ws);
    counts_kernel<<<256, 256, 0, stream>>>(target, ws);
    setup_kernel<<<1, 256, 0, stream>>>(pd, ws);
    p_kernel<<<512, 256, 0, stream>>>(feat, ubuf, abuf, pbuf, rnorm, 1);
    for (int it=0; it<10; it++) {
        a_kernel<<<(KK*PP)/256, 256, 0, stream>>>(pbuf, abuf);
        u_kernel<<<512, 256, 0, stream>>>(feat, pbuf, rnorm, upart);
        r_kernel<<<KK, 256, 0, stream>>>(upart, ws);
        if (it < 9)
            p_kernel<<<512, 256, 0, stream>>>(feat, ubuf, abuf, pbuf, rnorm, 0);
    }
    final_kernel<<<512, 256, 0, stream>>>(feat, logit, target, ubuf, abuf, scal);
    finalize_kernel<<<20, 256, 0, stream>>>(ws, out);
}

// Round 2
// 1970.224 us; speedup vs baseline: 1.1893x; 1.1893x over previous
//
#include <hip/hip_runtime.h>
#include <hip/hip_bf16.h>
#include <math.h>

#define BB 8
#define KK 19
#define PP 16384
#define CC 256
#define NN (BB*PP)           // 131072
#define KA_C 10.0f
#define IGNORE_L 255
#define CETHR 0.22314355131420976f   // -log(0.8)

// ws offsets (in floats)
#define OFF_FEATN   0                        // bf16[BB*CC*PP] = 16777216 floats worth
#define OFF_PROTO   16777216                 // 4864   [c][k]
#define OFF_COUNTS  (OFF_PROTO+4864)         // 32
#define OFF_SCAL    (OFF_COUNTS+32)          // 16 : 0 vmf, 1 consist, 2 ce_num, 3 ce_den, 4 contrast
#define OFF_UINIT   (OFF_SCAL+16)            // 4864  [c][k]
#define OFF_U       (OFF_UINIT+4864)         // 4864  [k][c]
#define OFF_A       (OFF_U+4864)             // KK*PP = 311296  [k][pix]
#define OFF_PBUF    (OFF_A+311296)           // BB*KK*PP = 2490368 fp32 [b][k][pix]
#define OFF_UPART   (OFF_PBUF+2490368)       // 512*4864 (also reused as rnorm[NN] in prologue)
// end = 22083888 floats = 88.3 MB

static __device__ __forceinline__ float bflo(unsigned int v){
    union{unsigned int i; float f;} x; x.i = v << 16; return x.f;
}
static __device__ __forceinline__ float bfhi(unsigned int v){
    union{unsigned int i; float f;} x; x.i = v & 0xffff0000u; return x.f;
}
static __device__ __forceinline__ unsigned short f2bf(float f){
    union{float f; unsigned int i;} x; x.f = f;
    unsigned int r = (x.i + 0x7fffu + ((x.i >> 16) & 1u)) >> 16;
    return (unsigned short)r;
}

// ---------------- proto segment-sum (raw f32 feat) ----------------
__global__ __launch_bounds__(256) void proto_kernel(const float* __restrict__ feat,
                                                    const int* __restrict__ target,
                                                    float* __restrict__ ws) {
    int blk = blockIdx.x;            // b*CC + c
    int b = blk >> 8;
    int c = blk & 255;
    int tid = threadIdx.x;
    const float* frow = feat + (size_t)(b*CC + c)*PP;
    const int*   trow = target + (size_t)b*PP;
    float acc[KK];
#pragma unroll
    for (int k=0;k<KK;k++) acc[k]=0.f;
    for (int p0 = tid*4; p0 < PP; p0 += 1024) {
        float4 v = *(const float4*)&frow[p0];
        int4   t = *(const int4*)&trow[p0];
#pragma unroll
        for (int k=0;k<KK;k++) {
            float s = acc[k];
            s += (t.x==k) ? v.x : 0.f;
            s += (t.y==k) ? v.y : 0.f;
            s += (t.z==k) ? v.z : 0.f;
            s += (t.w==k) ? v.w : 0.f;
            acc[k] = s;
        }
    }
    __shared__ float part[4][KK];
    int lane = tid & 63, w = tid >> 6;
#pragma unroll
    for (int k=0;k<KK;k++) {
        float v = acc[k];
#pragma unroll
        for (int s=32;s>0;s>>=1) v += __shfl_xor(v, s);
        if (lane==0) part[w][k]=v;
    }
    __syncthreads();
    if (tid < KK) {
        float s = part[0][tid]+part[1][tid]+part[2][tid]+part[3][tid];
        atomicAdd(&ws[OFF_PROTO + c*KK + tid], s);
    }
}

// ---------------- counts ----------------
__global__ __launch_bounds__(256) void counts_kernel(const int* __restrict__ target,
                                                     float* __restrict__ ws) {
    __shared__ int cnt[KK];
    if (threadIdx.x < KK) cnt[threadIdx.x]=0;
    __syncthreads();
    for (int i = blockIdx.x*256 + threadIdx.x; i < NN; i += gridDim.x*256) {
        int t = target[i];
        if (t >= 0 && t < KK) atomicAdd(&cnt[t], 1);
    }
    __syncthreads();
    if (threadIdx.x < KK) atomicAdd(&ws[OFF_COUNTS + threadIdx.x], (float)cnt[threadIdx.x]);
}

// ---------------- ss: per-pixel 1/||feat|| ----------------
__global__ __launch_bounds__(256) void ss_kernel(const float* __restrict__ feat,
                                                 float* __restrict__ rnorm) {
    int n2 = blockIdx.x*256 + threadIdx.x;   // 65536 threads
    int b = n2 >> 13;
    int pix = (n2 & 8191) << 1;
    const float* base = feat + (size_t)b*CC*PP + pix;
    float s0=0.f, s1=0.f;
    for (int c0=0; c0<CC; c0+=8) {
        float2 v[8];
#pragma unroll
        for (int j=0;j<8;j++) v[j] = *(const float2*)&base[(size_t)(c0+j)*PP];
#pragma unroll
        for (int j=0;j<8;j++) { s0 = fmaf(v[j].x, v[j].x, s0); s1 = fmaf(v[j].y, v[j].y, s1); }
    }
    int n = b*PP + pix;
    rnorm[n]   = 1.0f / fmaxf(sqrtf(s0), 1e-12f);
    rnorm[n+1] = 1.0f / fmaxf(sqrtf(s1), 1e-12f);
}

// ---------------- conv: featn = bf16(feat * rnorm) ----------------
__global__ __launch_bounds__(256) void conv_kernel(const float* __restrict__ feat,
                                                   const float* __restrict__ rnorm,
                                                   unsigned short* __restrict__ featn) {
    int n4 = blockIdx.x*256 + threadIdx.x;   // 32768 threads
    int b = n4 >> 12;
    int pix = (n4 & 4095) << 2;
    const float* base = feat + (size_t)b*CC*PP + pix;
    unsigned short* outp = featn + (size_t)b*CC*PP + pix;
    float4 r = *(const float4*)&rnorm[b*PP + pix];
    for (int c=0;c<CC;c++) {
        float4 v = *(const float4*)&base[(size_t)c*PP];
        ushort4 o;
        o.x = f2bf(v.x * r.x);
        o.y = f2bf(v.y * r.y);
        o.z = f2bf(v.z * r.z);
        o.w = f2bf(v.w * r.w);
        *(ushort4*)&outp[(size_t)c*PP] = o;
    }
}

// ---------------- setup: u_init, u0, contrast ----------------
__global__ __launch_bounds__(256) void setup_kernel(const float* __restrict__ pd,
                                                    float* __restrict__ ws) {
    int c = threadIdx.x;
    __shared__ float red[256];
    __shared__ float nrm[KK];
    __shared__ float lds_ui[256][KK];
    float cnts[KK], vi[KK];
#pragma unroll
    for (int k=0;k<KK;k++) cnts[k] = ws[OFF_COUNTS+k];
#pragma unroll
    for (int k=0;k<KK;k++) vi[k] = ws[OFF_PROTO + c*KK + k] / (cnts[k] + 1e-6f);
    for (int k=0;k<KK;k++) {
        red[c] = vi[k]*vi[k];
        __syncthreads();
        for (int s=128;s>0;s>>=1){ if (c<s) red[c]+=red[c+s]; __syncthreads(); }
        if (c==0) nrm[k] = fmaxf(sqrtf(red[0]), 1e-12f);
        __syncthreads();
    }
#pragma unroll
    for (int k=0;k<KK;k++) { vi[k] = vi[k]/nrm[k]; lds_ui[c][k] = vi[k]; ws[OFF_UINIT + c*KK + k] = vi[k]; }
    __syncthreads();
    float w0[KK];
#pragma unroll
    for (int k=0;k<KK;k++) w0[k] = (cnts[k]==0.f) ? pd[c*KK+k] : vi[k];
    for (int k=0;k<KK;k++) {
        red[c] = w0[k]*w0[k];
        __syncthreads();
        for (int s=128;s>0;s>>=1){ if (c<s) red[c]+=red[c+s]; __syncthreads(); }
        if (c==0) nrm[k] = fmaxf(sqrtf(red[0]), 1e-12f);
        __syncthreads();
    }
#pragma unroll
    for (int k=0;k<KK;k++) ws[OFF_U + k*CC + c] = w0[k] / nrm[k];
    float m[KK]; float Kn=0.f;
#pragma unroll
    for (int k=0;k<KK;k++){ m[k] = (cnts[k]==0.f)?0.f:1.f; Kn += m[k]; }
    float csum = 0.f;
    for (int idx = c; idx < KK*KK; idx += 256) {
        int k1 = idx / KK, k2 = idx % KK;
        if (m[k1]!=0.f && m[k2]!=0.f) {
            float g=0.f;
            for (int cc2=0; cc2<CC; cc2++) g += lds_ui[cc2][k1]*lds_ui[cc2][k2];
            csum += g;
        }
    }
    red[c]=csum; __syncthreads();
    for (int s=128;s>0;s>>=1){ if (c<s) red[c]+=red[c+s]; __syncthreads(); }
    if (c==0) ws[OFF_SCAL+4] = (red[0] - Kn) / (Kn * (Kn - 1.f));
}

// ---------------- P: dis -> p (bf16 featn, 2 px/thread) ----------------
__global__ __launch_bounds__(256) void p_kernel(const unsigned short* __restrict__ featn,
                                                const float* __restrict__ ws_u,
                                                const float* __restrict__ abuf,
                                                float* __restrict__ pbuf,
                                                int uniform_a) {
    __shared__ float lu[4864];
    for (int i=threadIdx.x; i<4864; i+=256) lu[i] = ws_u[i];
    __syncthreads();
    int n2 = blockIdx.x*256 + threadIdx.x;   // 65536 threads
    int b = n2 >> 13;
    int pix = (n2 & 8191) << 1;
    const unsigned short* fcol = featn + (size_t)b*CC*PP + pix;
    float d0[KK], d1[KK];
#pragma unroll
    for (int k=0;k<KK;k++){ d0[k]=0.f; d1[k]=0.f; }
    for (int c0=0; c0<CC; c0+=16) {
        unsigned int v[16];
#pragma unroll
        for (int j=0;j<16;j++) v[j] = *(const unsigned int*)&fcol[(size_t)(c0+j)*PP];
#pragma unroll
        for (int k=0;k<KK;k++) {
            float s0=d0[k], s1=d1[k];
#pragma unroll
            for (int j=0;j<16;j++) {
                float uv = lu[k*CC + c0 + j];
                s0 = fmaf(bflo(v[j]), uv, s0);
                s1 = fmaf(bfhi(v[j]), uv, s1);
            }
            d0[k]=s0; d1[k]=s1;
        }
    }
    float den0=0.f, den1=0.f;
    float e0[KK], e1[KK];
#pragma unroll
    for (int k=0;k<KK;k++) {
        float a0, a1;
        if (uniform_a) { a0 = a1 = (1.0f/(float)KK); }
        else { float2 av = *(const float2*)&abuf[k*PP + pix]; a0 = av.x; a1 = av.y; }
        e0[k] = a0 * __expf(KA_C * d0[k]);
        e1[k] = a1 * __expf(KA_C * d1[k]);
        den0 += e0[k]; den1 += e1[k];
    }
    float i0 = 1.0f/den0, i1 = 1.0f/den1;
#pragma unroll
    for (int k=0;k<KK;k++) {
        float2 o; o.x = e0[k]*i0; o.y = e1[k]*i1;
        *(float2*)&pbuf[((size_t)b*KK + k)*PP + pix] = o;
    }
}

// ---------------- A: a = mean_b p ----------------
__global__ __launch_bounds__(256) void a_kernel(const float* __restrict__ pbuf,
                                                float* __restrict__ abuf) {
    int i = blockIdx.x*256 + threadIdx.x;   // KK*PP total
    float s=0.f;
#pragma unroll
    for (int b=0;b<BB;b++) s += pbuf[(size_t)b*KK*PP + i];
    abuf[i] = s * (1.0f/(float)BB);
}

// ---------------- U: partials of featn · p ----------------
__global__ __launch_bounds__(256) void u_kernel(const unsigned short* __restrict__ featn,
                                                const float* __restrict__ pbuf,
                                                float* __restrict__ upart) {
    int blk = blockIdx.x;           // 512 blocks: b = blk>>6, 256-px chunk
    int b = blk >> 6;
    int pix0 = (blk & 63) * 256;
    int c = threadIdx.x;            // owns channel c
    const unsigned short* frow = featn + ((size_t)b*CC + c)*PP;
    __shared__ float wl[32][20];
    float acc[KK];
#pragma unroll
    for (int k=0;k<KK;k++) acc[k]=0.f;
    for (int st=0; st<8; st++) {
        int p0 = pix0 + st*32;
        for (int i=threadIdx.x; i<608; i+=256) {     // 19*32 p-weights
            int k = i >> 5, j = i & 31;
            wl[j][k] = pbuf[((size_t)b*KK + k)*PP + p0 + j];
        }
        __syncthreads();
        const uint4* rp = (const uint4*)&frow[p0];   // 64B = 32 bf16
        uint4 q[4];
#pragma unroll
        for (int t=0;t<4;t++) q[t] = rp[t];
        unsigned int vw[16];
#pragma unroll
        for (int t=0;t<4;t++) { vw[t*4+0]=q[t].x; vw[t*4+1]=q[t].y; vw[t*4+2]=q[t].z; vw[t*4+3]=q[t].w; }
#pragma unroll
        for (int jj=0;jj<16;jj++) {
            float flo = bflo(vw[jj]);
            float fhi = bfhi(vw[jj]);
            int j = jj*2;
#pragma unroll
            for (int k=0;k<KK;k++) acc[k] = fmaf(flo, wl[j][k], acc[k]);
#pragma unroll
            for (int k=0;k<KK;k++) acc[k] = fmaf(fhi, wl[j+1][k], acc[k]);
        }
        __syncthreads();
    }
#pragma unroll
    for (int k=0;k<KK;k++) upart[(size_t)blk*4864 + c*KK + k] = acc[k];
}

// ---------------- R: reduce partials + normalize -> u ----------------
__global__ __launch_bounds__(256) void r_kernel(const float* __restrict__ upart,
                                                float* __restrict__ ws) {
    int k = blockIdx.x;   // 0..18
    int c = threadIdx.x;  // 0..255
    float s = 0.f;
    for (int i=0;i<512;i++) s += upart[(size_t)i*4864 + c*KK + k];
    __shared__ float red[256];
    red[c] = s*s; __syncthreads();
    for (int q=128;q>0;q>>=1){ if (c<q) red[c]+=red[c+q]; __syncthreads(); }
    float nrm = fmaxf(sqrtf(red[0]), 1e-12f);
    ws[OFF_U + k*CC + c] = s / nrm;
}

// ---------------- final losses ----------------
__global__ __launch_bounds__(256) void final_kernel(const unsigned short* __restrict__ featn,
                                                    const float* __restrict__ logit,
                                                    const int* __restrict__ target,
                                                    const float* __restrict__ ws_u,
                                                    const float* __restrict__ abuf,
                                                    float* __restrict__ scal) {
    __shared__ float lu[4864];
    for (int i=threadIdx.x; i<4864; i+=256) lu[i] = ws_u[i];
    __syncthreads();
    int n = blockIdx.x*256 + threadIdx.x;   // 131072 threads
    int b = n >> 14;
    int pix = n & (PP-1);
    const unsigned short* fcol = featn + (size_t)b*CC*PP + pix;
    float dot[KK];
#pragma unroll
    for (int k=0;k<KK;k++) dot[k]=0.f;
    for (int c0=0; c0<CC; c0+=16) {
        float fv[16];
#pragma unroll
        for (int j=0;j<16;j++) {
            unsigned int u16 = fcol[(size_t)(c0+j)*PP];
            fv[j] = bflo(u16);
        }
#pragma unroll
        for (int k=0;k<KK;k++) {
            float d = dot[k];
#pragma unroll
            for (int j=0;j<16;j++) d = fmaf(fv[j], lu[k*CC+c0+j], d);
            dot[k]=d;
        }
    }
    float e[KK]; float den=0.f;
#pragma unroll
    for (int k=0;k<KK;k++) {
        float av = abuf[k*PP + pix];
        e[k] = av * __expf(KA_C * dot[k]);
        den += e[k];
    }
    float inv = 1.0f/den;
    float vmf = 0.f;
#pragma unroll
    for (int k=0;k<KK;k++) {
        float av = abuf[k*PP + pix];
        vmf += -(e[k]*inv) * (__logf(av + 1e-6f) + KA_C * dot[k]);
    }
    float lg[KK]; float mx = -3.4e38f;
#pragma unroll
    for (int k=0;k<KK;k++) { lg[k] = logit[((size_t)b*KK + k)*PP + pix]; mx = fmaxf(mx, lg[k]); }
    float sme = 0.f;
#pragma unroll
    for (int k=0;k<KK;k++) sme += __expf(lg[k]-mx);
    float lse = mx + __logf(sme);
    float cons = 0.f;
#pragma unroll
    for (int k=0;k<KK;k++) cons += -(e[k]*inv) * (lg[k]-lse);
    int t = target[(size_t)b*PP + pix];
    float ce_n = 0.f, ce_d = 0.f;
    if (t != IGNORE_L) {
        float lt = 0.f;
#pragma unroll
        for (int k=0;k<KK;k++) lt = (t==k) ? lg[k] : lt;
        float ce = -(lt - lse);
        ce_n = fmaxf(ce, CETHR);
        ce_d = 1.f;
    }
    __shared__ float red[4][4];
    int lane = threadIdx.x & 63, w = threadIdx.x >> 6;
    float v0=vmf, v1=cons, v2=ce_n, v3=ce_d;
#pragma unroll
    for (int s=32;s>0;s>>=1) {
        v0 += __shfl_xor(v0, s); v1 += __shfl_xor(v1, s);
        v2 += __shfl_xor(v2, s); v3 += __shfl_xor(v3, s);
    }
    if (lane==0){ red[w][0]=v0; red[w][1]=v1; red[w][2]=v2; red[w][3]=v3; }
    __syncthreads();
    if (threadIdx.x==0) {
        atomicAdd(&scal[0], red[0][0]+red[1][0]+red[2][0]+red[3][0]);
        atomicAdd(&scal[1], red[0][1]+red[1][1]+red[2][1]+red[3][1]);
        atomicAdd(&scal[2], red[0][2]+red[1][2]+red[2][2]+red[3][2]);
        atomicAdd(&scal[3], red[0][3]+red[1][3]+red[2][3]+red[3][3]);
    }
}

// ---------------- finalize ----------------
__global__ __launch_bounds__(256) void finalize_kernel(const float* __restrict__ ws,
                                                       float* __restrict__ out) {
    if (blockIdx.x==0 && threadIdx.x==0) {
        float cnt_all = (float)BB*(float)PP*(float)KK;
        float vmf  = ws[OFF_SCAL+0] / cnt_all / logf((float)KK);
        float cons = ws[OFF_SCAL+1] / cnt_all;
        float ce   = ws[OFF_SCAL+2] / (ws[OFF_SCAL+3] + 1e-6f);
        float contrast = ws[OFF_SCAL+4];
        out[0] = ce + vmf + contrast + cons;
    }
    int i = blockIdx.x*256 + threadIdx.x;
    if (i < 4864) out[1+i] = ws[OFF_PROTO+i];
    if (blockIdx.x==0 && threadIdx.x < KK) out[1+4864+threadIdx.x] = ws[OFF_COUNTS+threadIdx.x];
}

extern "C" void kernel_launch(void* const* d_in, const int* in_sizes, int n_in,
                              void* d_out, int out_size, void* d_ws, size_t ws_size,
                              hipStream_t stream) {
    (void)in_sizes; (void)n_in; (void)out_size; (void)ws_size;
    const float* logit  = (const float*)d_in[0];
    const int*   target = (const int*)d_in[1];
    const float* feat   = (const float*)d_in[2];
    const float* pd     = (const float*)d_in[4];
    float* out = (float*)d_out;
    float* ws  = (float*)d_ws;

    unsigned short* featn = (unsigned short*)ws;     // OFF_FEATN
    float* ubuf  = ws + OFF_U;
    float* abuf  = ws + OFF_A;
    float* pbuf  = ws + OFF_PBUF;
    float* upart = ws + OFF_UPART;
    float* rnorm = ws + OFF_UPART;                   // prologue-only reuse
    float* scal  = ws + OFF_SCAL;

    hipMemsetAsync(ws + OFF_PROTO, 0, 4912*sizeof(float), stream);
    proto_kernel<<<BB*CC, 256, 0, stream>>>(feat, target, ws);
    counts_kernel<<<256, 256, 0, stream>>>(target, ws);
    setup_kernel<<<1, 256, 0, stream>>>(pd, ws);
    ss_kernel<<<256, 256, 0, stream>>>(feat, rnorm);
    conv_kernel<<<128, 256, 0, stream>>>(feat, rnorm, featn);
    p_kernel<<<256, 256, 0, stream>>>(featn, ubuf, abuf, pbuf, 1);
    for (int it=0; it<10; it++) {
        a_kernel<<<(KK*PP)/256, 256, 0, stream>>>(pbuf, abuf);
        u_kernel<<<512, 256, 0, stream>>>(featn, pbuf, upart);
        r_kernel<<<KK, 256, 0, stream>>>(upart, ws);
        if (it < 9)
            p_kernel<<<256, 256, 0, stream>>>(featn, ubuf, abuf, pbuf, 0);
    }
    final_kernel<<<512, 256, 0, stream>>>(featn, logit, target, ubuf, abuf, scal);
    finalize_kernel<<<20, 256, 0, stream>>>(ws, out);
}

// Round 3
// 1174.474 us; speedup vs baseline: 1.9951x; 1.6775x over previous
//
#include <hip/hip_runtime.h>
#include <hip/hip_bf16.h>
#include <math.h>

#define BB 8
#define KK 19
#define PP 16384
#define CC 256
#define NN (BB*PP)           // 131072
#define KA_C 10.0f
#define IGNORE_L 255
#define CETHR 0.22314355131420976f   // -log(0.8)

// ws offsets (in floats)
#define OFF_FEATN   0                        // bf16[BB*CC*PP] = 16777216 floats worth
#define OFF_PROTO   16777216                 // 4864   [c][k]
#define OFF_COUNTS  (OFF_PROTO+4864)         // 32
#define OFF_SCAL    (OFF_COUNTS+32)          // 16 : 0 vmf, 1 consist, 2 ce_num, 3 ce_den, 4 contrast
#define OFF_UINIT   (OFF_SCAL+16)            // 4864  [c][k]
#define OFF_U       (OFF_UINIT+4864)         // 4864  [k][c]
#define OFF_A       (OFF_U+4864)             // KK*PP = 311296  [k][pix]
#define OFF_PBUF    (OFF_A+311296)           // BB*KK*PP = 2490368 fp32 [b][k][pix]
#define OFF_UPART   (OFF_PBUF+2490368)       // 512*4864
// end = 22083888 floats = 88.3 MB  (r1buf overlays head of PBUF between u and p)

static __device__ __forceinline__ float bflo(unsigned int v){
    union{unsigned int i; float f;} x; x.i = v << 16; return x.f;
}
static __device__ __forceinline__ float bfhi(unsigned int v){
    union{unsigned int i; float f;} x; x.i = v & 0xffff0000u; return x.f;
}
static __device__ __forceinline__ unsigned short f2bf(float f){
    union{float f; unsigned int i;} x; x.f = f;
    unsigned int r = (x.i + 0x7fffu + ((x.i >> 16) & 1u)) >> 16;
    return (unsigned short)r;
}

// ---------------- proto segment-sum (raw f32 feat) ----------------
__global__ __launch_bounds__(256) void proto_kernel(const float* __restrict__ feat,
                                                    const int* __restrict__ target,
                                                    float* __restrict__ ws) {
    int blk = blockIdx.x;            // b*CC + c
    int b = blk >> 8;
    int c = blk & 255;
    int tid = threadIdx.x;
    const float* frow = feat + (size_t)(b*CC + c)*PP;
    const int*   trow = target + (size_t)b*PP;
    float acc[KK];
#pragma unroll
    for (int k=0;k<KK;k++) acc[k]=0.f;
    for (int p0 = tid*4; p0 < PP; p0 += 1024) {
        float4 v = *(const float4*)&frow[p0];
        int4   t = *(const int4*)&trow[p0];
#pragma unroll
        for (int k=0;k<KK;k++) {
            float s = acc[k];
            s += (t.x==k) ? v.x : 0.f;
            s += (t.y==k) ? v.y : 0.f;
            s += (t.z==k) ? v.z : 0.f;
            s += (t.w==k) ? v.w : 0.f;
            acc[k] = s;
        }
    }
    __shared__ float part[4][KK];
    int lane = tid & 63, w = tid >> 6;
#pragma unroll
    for (int k=0;k<KK;k++) {
        float v = acc[k];
#pragma unroll
        for (int s=32;s>0;s>>=1) v += __shfl_xor(v, s);
        if (lane==0) part[w][k]=v;
    }
    __syncthreads();
    if (tid < KK) {
        float s = part[0][tid]+part[1][tid]+part[2][tid]+part[3][tid];
        atomicAdd(&ws[OFF_PROTO + c*KK + tid], s);
    }
}

// ---------------- counts ----------------
__global__ __launch_bounds__(256) void counts_kernel(const int* __restrict__ target,
                                                     float* __restrict__ ws) {
    __shared__ int cnt[KK];
    if (threadIdx.x < KK) cnt[threadIdx.x]=0;
    __syncthreads();
    for (int i = blockIdx.x*256 + threadIdx.x; i < NN; i += gridDim.x*256) {
        int t = target[i];
        if (t >= 0 && t < KK) atomicAdd(&cnt[t], 1);
    }
    __syncthreads();
    if (threadIdx.x < KK) atomicAdd(&ws[OFF_COUNTS + threadIdx.x], (float)cnt[threadIdx.x]);
}

// ---------------- ss+conv fused: featn = bf16(feat/||feat||) ----------------
__global__ __launch_bounds__(256) void ssconv_kernel(const float* __restrict__ feat,
                                                     unsigned short* __restrict__ featn) {
    int n2 = blockIdx.x*256 + threadIdx.x;   // 65536 threads, 2 px each
    int b = n2 >> 13;
    int pix = (n2 & 8191) << 1;
    const float* base = feat + (size_t)b*CC*PP + pix;
    unsigned short* outp = featn + (size_t)b*CC*PP + pix;
    float s0=0.f, s1=0.f;
    for (int c0=0; c0<CC; c0+=8) {
        float2 v[8];
#pragma unroll
        for (int j=0;j<8;j++) v[j] = *(const float2*)&base[(size_t)(c0+j)*PP];
#pragma unroll
        for (int j=0;j<8;j++) { s0 = fmaf(v[j].x, v[j].x, s0); s1 = fmaf(v[j].y, v[j].y, s1); }
    }
    float r0 = 1.0f / fmaxf(sqrtf(s0), 1e-12f);
    float r1 = 1.0f / fmaxf(sqrtf(s1), 1e-12f);
    // second pass: L2-hot re-read, scaled bf16 write
    for (int c0=0; c0<CC; c0+=4) {
#pragma unroll
        for (int j=0;j<4;j++) {
            float2 v = *(const float2*)&base[(size_t)(c0+j)*PP];
            unsigned int lo = f2bf(v.x * r0);
            unsigned int hi = f2bf(v.y * r1);
            *(unsigned int*)&outp[(size_t)(c0+j)*PP] = (hi<<16) | lo;
        }
    }
}

// ---------------- setup: u_init, u0, contrast ----------------
__global__ __launch_bounds__(256) void setup_kernel(const float* __restrict__ pd,
                                                    float* __restrict__ ws) {
    int c = threadIdx.x;
    __shared__ float red[256];
    __shared__ float nrm[KK];
    __shared__ float lds_ui[256][KK];
    float cnts[KK], vi[KK];
#pragma unroll
    for (int k=0;k<KK;k++) cnts[k] = ws[OFF_COUNTS+k];
#pragma unroll
    for (int k=0;k<KK;k++) vi[k] = ws[OFF_PROTO + c*KK + k] / (cnts[k] + 1e-6f);
    for (int k=0;k<KK;k++) {
        red[c] = vi[k]*vi[k];
        __syncthreads();
        for (int s=128;s>0;s>>=1){ if (c<s) red[c]+=red[c+s]; __syncthreads(); }
        if (c==0) nrm[k] = fmaxf(sqrtf(red[0]), 1e-12f);
        __syncthreads();
    }
#pragma unroll
    for (int k=0;k<KK;k++) { vi[k] = vi[k]/nrm[k]; lds_ui[c][k] = vi[k]; ws[OFF_UINIT + c*KK + k] = vi[k]; }
    __syncthreads();
    float w0[KK];
#pragma unroll
    for (int k=0;k<KK;k++) w0[k] = (cnts[k]==0.f) ? pd[c*KK+k] : vi[k];
    for (int k=0;k<KK;k++) {
        red[c] = w0[k]*w0[k];
        __syncthreads();
        for (int s=128;s>0;s>>=1){ if (c<s) red[c]+=red[c+s]; __syncthreads(); }
        if (c==0) nrm[k] = fmaxf(sqrtf(red[0]), 1e-12f);
        __syncthreads();
    }
#pragma unroll
    for (int k=0;k<KK;k++) ws[OFF_U + k*CC + c] = w0[k] / nrm[k];
    float m[KK]; float Kn=0.f;
#pragma unroll
    for (int k=0;k<KK;k++){ m[k] = (cnts[k]==0.f)?0.f:1.f; Kn += m[k]; }
    float csum = 0.f;
    for (int idx = c; idx < KK*KK; idx += 256) {
        int k1 = idx / KK, k2 = idx % KK;
        if (m[k1]!=0.f && m[k2]!=0.f) {
            float g=0.f;
            for (int cc2=0; cc2<CC; cc2++) g += lds_ui[cc2][k1]*lds_ui[cc2][k2];
            csum += g;
        }
    }
    red[c]=csum; __syncthreads();
    for (int s=128;s>0;s>>=1){ if (c<s) red[c]+=red[c+s]; __syncthreads(); }
    if (c==0) ws[OFF_SCAL+4] = (red[0] - Kn) / (Kn * (Kn - 1.f));
}

// ---------------- P: dis -> p (bf16 featn, 2 px/thread) ----------------
__global__ __launch_bounds__(256) void p_kernel(const unsigned short* __restrict__ featn,
                                                const float* __restrict__ ws_u,
                                                const float* __restrict__ abuf,
                                                float* __restrict__ pbuf,
                                                int uniform_a) {
    __shared__ float lu[4864];
    for (int i=threadIdx.x; i<4864; i+=256) lu[i] = ws_u[i];
    __syncthreads();
    int n2 = blockIdx.x*256 + threadIdx.x;   // 65536 threads
    int b = n2 >> 13;
    int pix = (n2 & 8191) << 1;
    const unsigned short* fcol = featn + (size_t)b*CC*PP + pix;
    float d0[KK], d1[KK];
#pragma unroll
    for (int k=0;k<KK;k++){ d0[k]=0.f; d1[k]=0.f; }
    for (int c0=0; c0<CC; c0+=16) {
        unsigned int v[16];
#pragma unroll
        for (int j=0;j<16;j++) v[j] = *(const unsigned int*)&fcol[(size_t)(c0+j)*PP];
#pragma unroll
        for (int k=0;k<KK;k++) {
            float s0=d0[k], s1=d1[k];
#pragma unroll
            for (int j=0;j<16;j++) {
                float uv = lu[k*CC + c0 + j];
                s0 = fmaf(bflo(v[j]), uv, s0);
                s1 = fmaf(bfhi(v[j]), uv, s1);
            }
            d0[k]=s0; d1[k]=s1;
        }
    }
    float den0=0.f, den1=0.f;
    float e0[KK], e1[KK];
#pragma unroll
    for (int k=0;k<KK;k++) {
        float a0, a1;
        if (uniform_a) { a0 = a1 = (1.0f/(float)KK); }
        else { float2 av = *(const float2*)&abuf[k*PP + pix]; a0 = av.x; a1 = av.y; }
        e0[k] = a0 * __expf(KA_C * d0[k]);
        e1[k] = a1 * __expf(KA_C * d1[k]);
        den0 += e0[k]; den1 += e1[k];
    }
    float i0 = 1.0f/den0, i1 = 1.0f/den1;
#pragma unroll
    for (int k=0;k<KK;k++) {
        float2 o; o.x = e0[k]*i0; o.y = e1[k]*i1;
        *(float2*)&pbuf[((size_t)b*KK + k)*PP + pix] = o;
    }
}

// ---------------- A: a = mean_b p ----------------
__global__ __launch_bounds__(256) void a_kernel(const float* __restrict__ pbuf,
                                                float* __restrict__ abuf) {
    int i = blockIdx.x*256 + threadIdx.x;   // KK*PP total
    float s=0.f;
#pragma unroll
    for (int b=0;b<BB;b++) s += pbuf[(size_t)b*KK*PP + i];
    abuf[i] = s * (1.0f/(float)BB);
}

// ---------------- U: partials of featn · p ----------------
__global__ __launch_bounds__(256) void u_kernel(const unsigned short* __restrict__ featn,
                                                const float* __restrict__ pbuf,
                                                float* __restrict__ upart) {
    int blk = blockIdx.x;           // 512 blocks: b = blk>>6, 256-px chunk
    int b = blk >> 6;
    int pix0 = (blk & 63) * 256;
    int c = threadIdx.x;            // owns channel c
    const unsigned short* frow = featn + ((size_t)b*CC + c)*PP;
    __shared__ float wl[32][20];
    float acc[KK];
#pragma unroll
    for (int k=0;k<KK;k++) acc[k]=0.f;
    for (int st=0; st<8; st++) {
        int p0 = pix0 + st*32;
        for (int i=threadIdx.x; i<608; i+=256) {     // 19*32 p-weights
            int k = i >> 5, j = i & 31;
            wl[j][k] = pbuf[((size_t)b*KK + k)*PP + p0 + j];
        }
        __syncthreads();
        const uint4* rp = (const uint4*)&frow[p0];   // 64B = 32 bf16
        uint4 q[4];
#pragma unroll
        for (int t=0;t<4;t++) q[t] = rp[t];
        unsigned int vw[16];
#pragma unroll
        for (int t=0;t<4;t++) { vw[t*4+0]=q[t].x; vw[t*4+1]=q[t].y; vw[t*4+2]=q[t].z; vw[t*4+3]=q[t].w; }
#pragma unroll
        for (int jj=0;jj<16;jj++) {
            float flo = bflo(vw[jj]);
            float fhi = bfhi(vw[jj]);
            int j = jj*2;
#pragma unroll
            for (int k=0;k<KK;k++) acc[k] = fmaf(flo, wl[j][k], acc[k]);
#pragma unroll
            for (int k=0;k<KK;k++) acc[k] = fmaf(fhi, wl[j+1][k], acc[k]);
        }
        __syncthreads();
    }
#pragma unroll
    for (int k=0;k<KK;k++) upart[(size_t)blk*4864 + c*KK + k] = acc[k];
}

// ---------------- R1: coalesced partial reduce 512 -> 8 ----------------
__global__ __launch_bounds__(256) void r1_kernel(const float* __restrict__ upart,
                                                 float* __restrict__ r1buf) {
    int blk = blockIdx.x;              // 152 = 8 ichunks * 19 echunks
    int echunk = blk % 19;
    int ichunk = blk / 19;
    int e = echunk*256 + threadIdx.x;  // 0..4863, coalesced
    float s = 0.f;
    int i0 = ichunk*64;
    for (int i=i0; i<i0+64; i++) s += upart[(size_t)i*4864 + e];
    r1buf[(size_t)ichunk*4864 + e] = s;
}

// ---------------- R2: final 8-way sum + normalize -> u ----------------
__global__ __launch_bounds__(256) void r2_kernel(const float* __restrict__ r1buf,
                                                 float* __restrict__ ws) {
    int k = blockIdx.x;   // 0..18
    int c = threadIdx.x;  // 0..255
    float s = 0.f;
#pragma unroll
    for (int i=0;i<8;i++) s += r1buf[(size_t)i*4864 + c*KK + k];
    __shared__ float red[256];
    red[c] = s*s; __syncthreads();
    for (int q=128;q>0;q>>=1){ if (c<q) red[c]+=red[c+q]; __syncthreads(); }
    float nrm = fmaxf(sqrtf(red[0]), 1e-12f);
    ws[OFF_U + k*CC + c] = s / nrm;
}

// ---------------- final losses ----------------
__global__ __launch_bounds__(256) void final_kernel(const unsigned short* __restrict__ featn,
                                                    const float* __restrict__ logit,
                                                    const int* __restrict__ target,
                                                    const float* __restrict__ ws_u,
                                                    const float* __restrict__ abuf,
                                                    float* __restrict__ scal) {
    __shared__ float lu[4864];
    for (int i=threadIdx.x; i<4864; i+=256) lu[i] = ws_u[i];
    __syncthreads();
    int n = blockIdx.x*256 + threadIdx.x;   // 131072 threads
    int b = n >> 14;
    int pix = n & (PP-1);
    const unsigned short* fcol = featn + (size_t)b*CC*PP + pix;
    float dot[KK];
#pragma unroll
    for (int k=0;k<KK;k++) dot[k]=0.f;
    for (int c0=0; c0<CC; c0+=16) {
        float fv[16];
#pragma unroll
        for (int j=0;j<16;j++) {
            unsigned int u16 = fcol[(size_t)(c0+j)*PP];
            fv[j] = bflo(u16);
        }
#pragma unroll
        for (int k=0;k<KK;k++) {
            float d = dot[k];
#pragma unroll
            for (int j=0;j<16;j++) d = fmaf(fv[j], lu[k*CC+c0+j], d);
            dot[k]=d;
        }
    }
    float e[KK]; float den=0.f;
#pragma unroll
    for (int k=0;k<KK;k++) {
        float av = abuf[k*PP + pix];
        e[k] = av * __expf(KA_C * dot[k]);
        den += e[k];
    }
    float inv = 1.0f/den;
    float vmf = 0.f;
#pragma unroll
    for (int k=0;k<KK;k++) {
        float av = abuf[k*PP + pix];
        vmf += -(e[k]*inv) * (__logf(av + 1e-6f) + KA_C * dot[k]);
    }
    float lg[KK]; float mx = -3.4e38f;
#pragma unroll
    for (int k=0;k<KK;k++) { lg[k] = logit[((size_t)b*KK + k)*PP + pix]; mx = fmaxf(mx, lg[k]); }
    float sme = 0.f;
#pragma unroll
    for (int k=0;k<KK;k++) sme += __expf(lg[k]-mx);
    float lse = mx + __logf(sme);
    float cons = 0.f;
#pragma unroll
    for (int k=0;k<KK;k++) cons += -(e[k]*inv) * (lg[k]-lse);
    int t = target[(size_t)b*PP + pix];
    float ce_n = 0.f, ce_d = 0.f;
    if (t != IGNORE_L) {
        float lt = 0.f;
#pragma unroll
        for (int k=0;k<KK;k++) lt = (t==k) ? lg[k] : lt;
        float ce = -(lt - lse);
        ce_n = fmaxf(ce, CETHR);
        ce_d = 1.f;
    }
    __shared__ float red[4][4];
    int lane = threadIdx.x & 63, w = threadIdx.x >> 6;
    float v0=vmf, v1=cons, v2=ce_n, v3=ce_d;
#pragma unroll
    for (int s=32;s>0;s>>=1) {
        v0 += __shfl_xor(v0, s); v1 += __shfl_xor(v1, s);
        v2 += __shfl_xor(v2, s); v3 += __shfl_xor(v3, s);
    }
    if (lane==0){ red[w][0]=v0; red[w][1]=v1; red[w][2]=v2; red[w][3]=v3; }
    __syncthreads();
    if (threadIdx.x==0) {
        atomicAdd(&scal[0], red[0][0]+red[1][0]+red[2][0]+red[3][0]);
        atomicAdd(&scal[1], red[0][1]+red[1][1]+red[2][1]+red[3][1]);
        atomicAdd(&scal[2], red[0][2]+red[1][2]+red[2][2]+red[3][2]);
        atomicAdd(&scal[3], red[0][3]+red[1][3]+red[2][3]+red[3][3]);
    }
}

// ---------------- finalize ----------------
__global__ __launch_bounds__(256) void finalize_kernel(const float* __restrict__ ws,
                                                       float* __restrict__ out) {
    if (blockIdx.x==0 && threadIdx.x==0) {
        float cnt_all = (float)BB*(float)PP*(float)KK;
        float vmf  = ws[OFF_SCAL+0] / cnt_all / logf((float)KK);
        float cons = ws[OFF_SCAL+1] / cnt_all;
        float ce   = ws[OFF_SCAL+2] / (ws[OFF_SCAL+3] + 1e-6f);
        float contrast = ws[OFF_SCAL+4];
        out[0] = ce + vmf + contrast + cons;
    }
    int i = blockIdx.x*256 + threadIdx.x;
    if (i < 4864) out[1+i] = ws[OFF_PROTO+i];
    if (blockIdx.x==0 && threadIdx.x < KK) out[1+4864+threadIdx.x] = ws[OFF_COUNTS+threadIdx.x];
}

extern "C" void kernel_launch(void* const* d_in, const int* in_sizes, int n_in,
                              void* d_out, int out_size, void* d_ws, size_t ws_size,
                              hipStream_t stream) {
    (void)in_sizes; (void)n_in; (void)out_size; (void)ws_size;
    const float* logit  = (const float*)d_in[0];
    const int*   target = (const int*)d_in[1];
    const float* feat   = (const float*)d_in[2];
    const float* pd     = (const float*)d_in[4];
    float* out = (float*)d_out;
    float* ws  = (float*)d_ws;

    unsigned short* featn = (unsigned short*)ws;     // OFF_FEATN
    float* ubuf  = ws + OFF_U;
    float* abuf  = ws + OFF_A;
    float* pbuf  = ws + OFF_PBUF;
    float* upart = ws + OFF_UPART;
    float* r1buf = ws + OFF_PBUF;                    // overlays pbuf head; dead window only
    float* scal  = ws + OFF_SCAL;

    hipMemsetAsync(ws + OFF_PROTO, 0, 4912*sizeof(float), stream);
    proto_kernel<<<BB*CC, 256, 0, stream>>>(feat, target, ws);
    counts_kernel<<<256, 256, 0, stream>>>(target, ws);
    setup_kernel<<<1, 256, 0, stream>>>(pd, ws);
    ssconv_kernel<<<256, 256, 0, stream>>>(feat, featn);
    p_kernel<<<256, 256, 0, stream>>>(featn, ubuf, abuf, pbuf, 1);
    for (int it=0; it<10; it++) {
        a_kernel<<<(KK*PP)/256, 256, 0, stream>>>(pbuf, abuf);
        u_kernel<<<512, 256, 0, stream>>>(featn, pbuf, upart);
        r1_kernel<<<152, 256, 0, stream>>>(upart, r1buf);
        r2_kernel<<<KK, 256, 0, stream>>>(r1buf, ws);
        if (it < 9)
            p_kernel<<<256, 256, 0, stream>>>(featn, ubuf, abuf, pbuf, 0);
    }
    final_kernel<<<512, 256, 0, stream>>>(featn, logit, target, ubuf, abuf, scal);
    finalize_kernel<<<20, 256, 0, stream>>>(ws, out);
}